// Round 1
// baseline (368.782 us; speedup 1.0000x reference)
//
#include <hip/hip_runtime.h>
#include <cstddef>

namespace {
constexpr int B_ = 8;
constexpr int N_ = 512;
constexpr int D_ = 768;
constexpr int HS_ = 64;
constexpr int M_ = B_ * N_;   // 4096 rows (b*N + n)
constexpr int E_ = 2 * HS_;   // 128
constexpr float NEGV = 1000000000000.0f;
constexpr float LOG2_10000 = 13.287712379549449f;
}

// ---------------------------------------------------------------------------
// Stage 1: h[fam][row][e] = chars[row][:] . w1[fam][e][:] + b1[fam][e]
// grid (128, 3), block 256.  BM=32, BN=128, KB=32.
// ---------------------------------------------------------------------------
__global__ __launch_bounds__(256) void gemm_h_kernel(
    const float* __restrict__ chars,
    const float* __restrict__ w1e, const float* __restrict__ b1e,
    const float* __restrict__ w1h, const float* __restrict__ b1h,
    const float* __restrict__ w1t, const float* __restrict__ b1t,
    float* __restrict__ h_base)
{
    const int fam = blockIdx.y;
    const float* w1 = (fam == 0) ? w1e : (fam == 1) ? w1h : w1t;
    const float* b1 = (fam == 0) ? b1e : (fam == 1) ? b1h : b1t;
    float* hout = h_base + (size_t)fam * M_ * E_;
    const int m0 = blockIdx.x * 32;

    __shared__ float As[32][33];    // [row][k], +1 pad
    __shared__ float Ws[32][128];   // [k][col]

    const int t  = threadIdx.x;
    const int rg = t >> 5;   // 0..7  -> rows rg*4 .. rg*4+3
    const int cg = t & 31;   // 0..31 -> cols cg*4 .. cg*4+3

    float acc[4][4] = {};

    for (int k0 = 0; k0 < D_; k0 += 32) {
        // stage A tile: 32 rows x 32 k
        {
            const int ar = t >> 3;   // 0..31
            const int ac = t & 7;    // 0..7
            const float4 v = *(const float4*)(chars + (size_t)(m0 + ar) * D_ + k0 + ac * 4);
            As[ar][ac * 4 + 0] = v.x;
            As[ar][ac * 4 + 1] = v.y;
            As[ar][ac * 4 + 2] = v.z;
            As[ar][ac * 4 + 3] = v.w;
        }
        // stage W tile transposed: [k][col], 32 k x 128 cols
        {
            const int col  = t >> 1;  // 0..127
            const int half = t & 1;   // 0..1
            const float* wp = w1 + (size_t)col * D_ + k0 + half * 16;
            #pragma unroll
            for (int qq = 0; qq < 4; ++qq) {
                const float4 v = *(const float4*)(wp + qq * 4);
                const int kk = half * 16 + qq * 4;
                Ws[kk + 0][col] = v.x;
                Ws[kk + 1][col] = v.y;
                Ws[kk + 2][col] = v.z;
                Ws[kk + 3][col] = v.w;
            }
        }
        __syncthreads();
        #pragma unroll 8
        for (int k = 0; k < 32; ++k) {
            const float a0 = As[rg * 4 + 0][k];
            const float a1 = As[rg * 4 + 1][k];
            const float a2 = As[rg * 4 + 2][k];
            const float a3 = As[rg * 4 + 3][k];
            const float4 wv = *(const float4*)&Ws[k][cg * 4];
            acc[0][0] += a0 * wv.x; acc[0][1] += a0 * wv.y; acc[0][2] += a0 * wv.z; acc[0][3] += a0 * wv.w;
            acc[1][0] += a1 * wv.x; acc[1][1] += a1 * wv.y; acc[1][2] += a1 * wv.z; acc[1][3] += a1 * wv.w;
            acc[2][0] += a2 * wv.x; acc[2][1] += a2 * wv.y; acc[2][2] += a2 * wv.z; acc[2][3] += a2 * wv.w;
            acc[3][0] += a3 * wv.x; acc[3][1] += a3 * wv.y; acc[3][2] += a3 * wv.z; acc[3][3] += a3 * wv.w;
        }
        __syncthreads();
    }

    const float4 bv = *(const float4*)(b1 + cg * 4);
    #pragma unroll
    for (int j = 0; j < 4; ++j) {
        const float4 o = make_float4(acc[j][0] + bv.x, acc[j][1] + bv.y,
                                     acc[j][2] + bv.z, acc[j][3] + bv.w);
        *(float4*)(hout + (size_t)(m0 + rg * 4 + j) * E_ + cg * 4) = o;
    }
}

// ---------------------------------------------------------------------------
// Stage 2: bias[fam][b][h2][n] = (h[fam][b*N+n][:] . w2[fam][h2][:] + b2) * 0.5
// grid (4096, 3), block 64.
// ---------------------------------------------------------------------------
__global__ __launch_bounds__(64) void bias_kernel(
    const float* __restrict__ h_base,
    const float* __restrict__ w2e, const float* __restrict__ b2e,
    const float* __restrict__ w2h, const float* __restrict__ b2h,
    const float* __restrict__ w2t, const float* __restrict__ b2t,
    float* __restrict__ bias_e, float* __restrict__ bias_h, float* __restrict__ bias_t)
{
    const int fam = blockIdx.y;
    const int row = blockIdx.x;   // b*N + n
    const float* w2; const float* b2; float* bout; int H2;
    if (fam == 0)      { w2 = w2e; b2 = b2e; bout = bias_e; H2 = 4;  }
    else if (fam == 1) { w2 = w2h; b2 = b2h; bout = bias_h; H2 = 24; }
    else               { w2 = w2t; b2 = b2t; bout = bias_t; H2 = 24; }

    __shared__ float hrow[E_];
    const float* hr = h_base + ((size_t)fam * M_ + row) * E_;
    hrow[threadIdx.x]      = hr[threadIdx.x];
    hrow[threadIdx.x + 64] = hr[threadIdx.x + 64];
    __syncthreads();

    const int h2 = threadIdx.x;
    if (h2 < H2) {
        const float* w = w2 + (size_t)h2 * E_;
        float s = 0.0f;
        #pragma unroll 8
        for (int e = 0; e < E_; ++e) s += hrow[e] * w[e];
        s = (s + b2[h2]) * 0.5f;
        const int b = row >> 9;      // /512
        const int n = row & 511;
        bout[((size_t)b * H2 + h2) * N_ + n] = s;
    }
}

// ---------------------------------------------------------------------------
// Stage 3: fused QK^T + bias broadcast + masks + store.
// grid (8, 8, 8)  (m-tile, n-tile, b), block 256.  64x64 tile, K=64.
// out[b,h,m,n] = qk/8 + bias[b,2h,n] + bias[b,2h+1,m] - pad*NEG - tril*NEG
// ---------------------------------------------------------------------------
template <int H, bool ROPE, bool TRIL>
__global__ __launch_bounds__(256) void egp_out_kernel(
    const float* __restrict__ hfam, const float* __restrict__ biasfam,
    const int* __restrict__ mask, float* __restrict__ out)
{
    const int b  = blockIdx.z;
    const int m0 = blockIdx.x * 64;
    const int n0 = blockIdx.y * 64;

    __shared__ float qt[64][65];   // [m][k]
    __shared__ float kt[64][64];   // [k][n]

    const int t    = threadIdx.x;
    const int srow = t >> 2;   // 0..63
    const int sch  = t & 3;    // 0..3

    // stage Q (rows m0+srow) and K (rows n0+srow), applying rope if needed.
    {
        const float* hq = hfam + (size_t)(b * N_ + m0 + srow) * E_;
        const float* hk = hfam + (size_t)(b * N_ + n0 + srow) * E_;
        #pragma unroll
        for (int jj = 0; jj < 8; ++jj) {
            const int i = sch + 4 * jj;   // rope pair index 0..31
            const float4 v = *(const float4*)(hq + 4 * i);  // q[2i],k[2i],q[2i+1],k[2i+1]
            const float4 w = *(const float4*)(hk + 4 * i);
            if (ROPE) {
                const float inv = exp2f(-(float)i * (LOG2_10000 / 32.0f));
                float sq, cq, sk, ck;
                sincosf((float)(m0 + srow) * inv, &sq, &cq);
                sincosf((float)(n0 + srow) * inv, &sk, &ck);
                qt[srow][2 * i + 0] = v.x * cq - v.z * sq;
                qt[srow][2 * i + 1] = v.z * cq + v.x * sq;
                kt[2 * i + 0][srow] = w.y * ck - w.w * sk;
                kt[2 * i + 1][srow] = w.w * ck + w.y * sk;
            } else {
                qt[srow][2 * i + 0] = v.x;
                qt[srow][2 * i + 1] = v.z;
                kt[2 * i + 0][srow] = w.y;
                kt[2 * i + 1][srow] = w.w;
            }
        }
    }
    __syncthreads();

    const int cg = t & 15;   // cols n0 + 4*cg .. +3
    const int rg = t >> 4;   // rows m0 + rg + 16*j

    float acc[4][4] = {};
    #pragma unroll 8
    for (int k = 0; k < 64; ++k) {
        const float a0 = qt[rg + 0][k];
        const float a1 = qt[rg + 16][k];
        const float a2 = qt[rg + 32][k];
        const float a3 = qt[rg + 48][k];
        const float4 kv = *(const float4*)&kt[k][4 * cg];
        acc[0][0] += a0 * kv.x; acc[0][1] += a0 * kv.y; acc[0][2] += a0 * kv.z; acc[0][3] += a0 * kv.w;
        acc[1][0] += a1 * kv.x; acc[1][1] += a1 * kv.y; acc[1][2] += a1 * kv.z; acc[1][3] += a1 * kv.w;
        acc[2][0] += a2 * kv.x; acc[2][1] += a2 * kv.y; acc[2][2] += a2 * kv.z; acc[2][3] += a2 * kv.w;
        acc[3][0] += a3 * kv.x; acc[3][1] += a3 * kv.y; acc[3][2] += a3 * kv.z; acc[3][3] += a3 * kv.w;
    }

    // scale 1/sqrt(64)
    #pragma unroll
    for (int j = 0; j < 4; ++j)
        #pragma unroll
        for (int q = 0; q < 4; ++q) acc[j][q] *= 0.125f;

    int mrow[4], mm[4];
    #pragma unroll
    for (int j = 0; j < 4; ++j) {
        mrow[j] = m0 + rg + 16 * j;
        mm[j]   = mask[b * N_ + mrow[j]];
    }
    const int ncol = n0 + 4 * cg;
    const int4 mnv = *(const int4*)(mask + b * N_ + ncol);
    const int mn[4] = { mnv.x, mnv.y, mnv.z, mnv.w };

    #pragma unroll
    for (int hh = 0; hh < H; ++hh) {
        const float4 be = *(const float4*)(biasfam + ((size_t)b * 2 * H + 2 * hh) * N_ + ncol);
        float bo[4];
        #pragma unroll
        for (int j = 0; j < 4; ++j)
            bo[j] = biasfam[((size_t)b * 2 * H + 2 * hh + 1) * N_ + mrow[j]];

        #pragma unroll
        for (int j = 0; j < 4; ++j) {
            float o[4] = { acc[j][0] + be.x + bo[j], acc[j][1] + be.y + bo[j],
                           acc[j][2] + be.z + bo[j], acc[j][3] + be.w + bo[j] };
            #pragma unroll
            for (int q = 0; q < 4; ++q) {
                if (!(mm[j] & mn[q])) o[q] -= NEGV;
                if (TRIL && (ncol + q) < mrow[j]) o[q] -= NEGV;
            }
            float4 ov = make_float4(o[0], o[1], o[2], o[3]);
            *(float4*)(out + (((size_t)(b * H + hh) * N_ + mrow[j])) * N_ + ncol) = ov;
        }
    }
}

// ---------------------------------------------------------------------------
extern "C" void kernel_launch(void* const* d_in, const int* in_sizes, int n_in,
                              void* d_out, int out_size, void* d_ws, size_t ws_size,
                              hipStream_t stream)
{
    const float* chars = (const float*)d_in[0];
    const int*   mask  = (const int*)d_in[1];
    const float* w1e = (const float*)d_in[2];
    const float* b1e = (const float*)d_in[3];
    const float* w2e = (const float*)d_in[4];
    const float* b2e = (const float*)d_in[5];
    const float* w1h = (const float*)d_in[6];
    const float* b1h = (const float*)d_in[7];
    const float* w2h = (const float*)d_in[8];
    const float* b2h = (const float*)d_in[9];
    const float* w1t = (const float*)d_in[10];
    const float* b1t = (const float*)d_in[11];
    const float* w2t = (const float*)d_in[12];
    const float* b2t = (const float*)d_in[13];

    float* out = (float*)d_out;

    // workspace layout (floats)
    float* h_ws   = (float*)d_ws;                       // 3 * 4096 * 128
    float* bias_e = h_ws + (size_t)3 * M_ * E_;         // 8*4*512
    float* bias_h = bias_e + (size_t)B_ * 4 * N_;       // 8*24*512
    float* bias_t = bias_h + (size_t)B_ * 24 * N_;      // 8*24*512

    gemm_h_kernel<<<dim3(M_ / 32, 3), 256, 0, stream>>>(
        chars, w1e, b1e, w1h, b1h, w1t, b1t, h_ws);

    bias_kernel<<<dim3(M_, 3), 64, 0, stream>>>(
        h_ws, w2e, b2e, w2h, b2h, w2t, b2t, bias_e, bias_h, bias_t);

    const size_t ent_sz  = (size_t)B_ * 2 * N_ * N_;    // 4,194,304
    const size_t head_sz = (size_t)B_ * 12 * N_ * N_;   // 25,165,824

    egp_out_kernel<2, true, true><<<dim3(8, 8, 8), 256, 0, stream>>>(
        h_ws, bias_e, mask, out);
    egp_out_kernel<12, false, false><<<dim3(8, 8, 8), 256, 0, stream>>>(
        h_ws + (size_t)M_ * E_, bias_h, mask, out + ent_sz);
    egp_out_kernel<12, false, false><<<dim3(8, 8, 8), 256, 0, stream>>>(
        h_ws + (size_t)2 * M_ * E_, bias_t, mask, out + ent_sz + head_sz);
}

// Round 2
// 318.524 us; speedup vs baseline: 1.1578x; 1.1578x over previous
//
#include <hip/hip_runtime.h>
#include <cstddef>

namespace {
constexpr int B_ = 8;
constexpr int N_ = 512;
constexpr int D_ = 768;
constexpr int HS_ = 64;
constexpr int M_ = B_ * N_;   // 4096 rows (b*N + n)
constexpr int E_ = 2 * HS_;   // 128
constexpr float NEGV = 1000000000000.0f;
constexpr float LOG2_10000 = 13.287712379549449f;
}

// ---------------------------------------------------------------------------
// Stage 1: h = chars @ w1^T + b1  (per family), bias = (h @ w2^T + b2)*0.5
// fused: bias computed from the h tile still in LDS.
// grid (128, 3), block 256.  BM=32, BN=128(all of E), KB=32.
// ---------------------------------------------------------------------------
template <int H2>
__device__ __forceinline__ void bias_from_lds(
    const float (*hs)[132], const float* __restrict__ w2,
    const float* __restrict__ b2, float* __restrict__ bout,
    int m0, int t)
{
    // 32 rows x H2 outputs; each thread handles ceil(32*H2/256) dots of 128.
    const int bb = m0 >> 9;          // batch (tile never crosses batch: 32 | 512)
    const int nbase = m0 & 511;
    for (int idx = t; idx < 32 * H2; idx += 256) {
        const int row = idx / H2;
        const int h2  = idx - row * H2;
        const float* w = w2 + (size_t)h2 * E_;
        float s = 0.0f;
        #pragma unroll 8
        for (int e4 = 0; e4 < 32; ++e4) {
            const float4 hv = *(const float4*)&hs[row][4 * e4];
            const float4 wv = *(const float4*)(w + 4 * e4);
            s += hv.x * wv.x + hv.y * wv.y + hv.z * wv.z + hv.w * wv.w;
        }
        s = (s + b2[h2]) * 0.5f;
        bout[((size_t)bb * H2 + h2) * N_ + nbase + row] = s;
    }
}

__global__ __launch_bounds__(256) void prep_kernel(
    const float* __restrict__ chars,
    const float* __restrict__ w1e, const float* __restrict__ b1e,
    const float* __restrict__ w2e, const float* __restrict__ b2e,
    const float* __restrict__ w1h, const float* __restrict__ b1h,
    const float* __restrict__ w2h, const float* __restrict__ b2h,
    const float* __restrict__ w1t, const float* __restrict__ b1t,
    const float* __restrict__ w2t, const float* __restrict__ b2t,
    float* __restrict__ h_base,
    float* __restrict__ bias_e, float* __restrict__ bias_h, float* __restrict__ bias_t)
{
    const int fam = blockIdx.y;
    const float* w1 = (fam == 0) ? w1e : (fam == 1) ? w1h : w1t;
    const float* b1 = (fam == 0) ? b1e : (fam == 1) ? b1h : b1t;
    float* hout = h_base + (size_t)fam * M_ * E_;
    const int m0 = blockIdx.x * 32;

    __shared__ float As[32][33];    // [row][k]
    __shared__ float Ws[32][128];   // [k][col]
    __shared__ float hs[32][132];   // [row][e], for fused bias

    const int t  = threadIdx.x;
    const int rg = t >> 5;   // 0..7  -> rows rg*4 .. rg*4+3
    const int cg = t & 31;   // 0..31 -> cols cg*4 .. cg*4+3

    float acc[4][4] = {};

    for (int k0 = 0; k0 < D_; k0 += 32) {
        {
            const int ar = t >> 3;
            const int ac = t & 7;
            const float4 v = *(const float4*)(chars + (size_t)(m0 + ar) * D_ + k0 + ac * 4);
            As[ar][ac * 4 + 0] = v.x;
            As[ar][ac * 4 + 1] = v.y;
            As[ar][ac * 4 + 2] = v.z;
            As[ar][ac * 4 + 3] = v.w;
        }
        {
            const int col  = t >> 1;
            const int half = t & 1;
            const float* wp = w1 + (size_t)col * D_ + k0 + half * 16;
            #pragma unroll
            for (int qq = 0; qq < 4; ++qq) {
                const float4 v = *(const float4*)(wp + qq * 4);
                const int kk = half * 16 + qq * 4;
                Ws[kk + 0][col] = v.x;
                Ws[kk + 1][col] = v.y;
                Ws[kk + 2][col] = v.z;
                Ws[kk + 3][col] = v.w;
            }
        }
        __syncthreads();
        #pragma unroll 8
        for (int k = 0; k < 32; ++k) {
            const float a0 = As[rg * 4 + 0][k];
            const float a1 = As[rg * 4 + 1][k];
            const float a2 = As[rg * 4 + 2][k];
            const float a3 = As[rg * 4 + 3][k];
            const float4 wv = *(const float4*)&Ws[k][cg * 4];
            acc[0][0] += a0 * wv.x; acc[0][1] += a0 * wv.y; acc[0][2] += a0 * wv.z; acc[0][3] += a0 * wv.w;
            acc[1][0] += a1 * wv.x; acc[1][1] += a1 * wv.y; acc[1][2] += a1 * wv.z; acc[1][3] += a1 * wv.w;
            acc[2][0] += a2 * wv.x; acc[2][1] += a2 * wv.y; acc[2][2] += a2 * wv.z; acc[2][3] += a2 * wv.w;
            acc[3][0] += a3 * wv.x; acc[3][1] += a3 * wv.y; acc[3][2] += a3 * wv.z; acc[3][3] += a3 * wv.w;
        }
        __syncthreads();
    }

    const float4 bv = *(const float4*)(b1 + cg * 4);
    #pragma unroll
    for (int j = 0; j < 4; ++j) {
        const float4 o = make_float4(acc[j][0] + bv.x, acc[j][1] + bv.y,
                                     acc[j][2] + bv.z, acc[j][3] + bv.w);
        *(float4*)(hout + (size_t)(m0 + rg * 4 + j) * E_ + cg * 4) = o;
        *(float4*)&hs[rg * 4 + j][cg * 4] = o;
    }
    __syncthreads();

    if (fam == 0)      bias_from_lds<4 >(hs, w2e, b2e, bias_e, m0, t);
    else if (fam == 1) bias_from_lds<24>(hs, w2h, b2h, bias_h, m0, t);
    else               bias_from_lds<24>(hs, w2t, b2t, bias_t, m0, t);
}

// ---------------------------------------------------------------------------
// Stage 2: fused QK^T + bias broadcast + masks + store; all 3 families.
// grid (8, 8, 24): (m-tile, n-tile, fam*8+b), block 256. 64x64 tile, K=64.
// ---------------------------------------------------------------------------
template <int H, bool ROPE, bool TRIL>
__device__ __forceinline__ void egp_tile(
    const float* __restrict__ hfam, const float* __restrict__ biasfam,
    const int* __restrict__ mask, float* __restrict__ out,
    int b, int m0, int n0, float (*qtT)[68], float (*kt)[68], int t)
{
    const int srow = t >> 2;   // 0..63
    const int sch  = t & 3;    // 0..3

    {
        const float* hq = hfam + (size_t)(b * N_ + m0 + srow) * E_;
        const float* hk = hfam + (size_t)(b * N_ + n0 + srow) * E_;
        #pragma unroll
        for (int jj = 0; jj < 8; ++jj) {
            const int i = sch + 4 * jj;   // rope pair index 0..31
            const float4 v = *(const float4*)(hq + 4 * i);  // q[2i],k[2i],q[2i+1],k[2i+1]
            const float4 w = *(const float4*)(hk + 4 * i);
            if (ROPE) {
                const float inv = exp2f(-(float)i * (LOG2_10000 / 32.0f));
                float sq, cq, sk, ck;
                sincosf((float)(m0 + srow) * inv, &sq, &cq);
                sincosf((float)(n0 + srow) * inv, &sk, &ck);
                qtT[2 * i + 0][srow] = v.x * cq - v.z * sq;
                qtT[2 * i + 1][srow] = v.z * cq + v.x * sq;
                kt [2 * i + 0][srow] = w.y * ck - w.w * sk;
                kt [2 * i + 1][srow] = w.w * ck + w.y * sk;
            } else {
                qtT[2 * i + 0][srow] = v.x;
                qtT[2 * i + 1][srow] = v.z;
                kt [2 * i + 0][srow] = w.y;
                kt [2 * i + 1][srow] = w.w;
            }
        }
    }
    __syncthreads();

    const int rq = t >> 4;   // 0..15 -> rows m0 + 4*rq + j
    const int cq = t & 15;   // 0..15 -> cols n0 + 4*cq + q

    float acc[4][4] = {};
    #pragma unroll 8
    for (int k = 0; k < 64; ++k) {
        const float4 av = *(const float4*)&qtT[k][4 * rq];
        const float4 kv = *(const float4*)&kt [k][4 * cq];
        acc[0][0] += av.x * kv.x; acc[0][1] += av.x * kv.y; acc[0][2] += av.x * kv.z; acc[0][3] += av.x * kv.w;
        acc[1][0] += av.y * kv.x; acc[1][1] += av.y * kv.y; acc[1][2] += av.y * kv.z; acc[1][3] += av.y * kv.w;
        acc[2][0] += av.z * kv.x; acc[2][1] += av.z * kv.y; acc[2][2] += av.z * kv.z; acc[2][3] += av.z * kv.w;
        acc[3][0] += av.w * kv.x; acc[3][1] += av.w * kv.y; acc[3][2] += av.w * kv.z; acc[3][3] += av.w * kv.w;
    }

    #pragma unroll
    for (int j = 0; j < 4; ++j)
        #pragma unroll
        for (int q = 0; q < 4; ++q) acc[j][q] *= 0.125f;   // 1/sqrt(64)

    int mrow[4], mm[4];
    #pragma unroll
    for (int j = 0; j < 4; ++j) {
        mrow[j] = m0 + 4 * rq + j;
        mm[j]   = mask[b * N_ + mrow[j]];
    }
    const int ncol = n0 + 4 * cq;
    const int4 mnv = *(const int4*)(mask + b * N_ + ncol);
    const int mn[4] = { mnv.x, mnv.y, mnv.z, mnv.w };

    #pragma unroll
    for (int hh = 0; hh < H; ++hh) {
        const float4 be = *(const float4*)(biasfam + ((size_t)b * 2 * H + 2 * hh) * N_ + ncol);
        float bo[4];
        #pragma unroll
        for (int j = 0; j < 4; ++j)
            bo[j] = biasfam[((size_t)b * 2 * H + 2 * hh + 1) * N_ + mrow[j]];

        #pragma unroll
        for (int j = 0; j < 4; ++j) {
            float o[4] = { acc[j][0] + be.x + bo[j], acc[j][1] + be.y + bo[j],
                           acc[j][2] + be.z + bo[j], acc[j][3] + be.w + bo[j] };
            #pragma unroll
            for (int q = 0; q < 4; ++q) {
                if (!(mm[j] & mn[q])) o[q] -= NEGV;
                if (TRIL && (ncol + q) < mrow[j]) o[q] -= NEGV;
            }
            *(float4*)(out + ((size_t)(b * H + hh) * N_ + mrow[j]) * N_ + ncol) =
                make_float4(o[0], o[1], o[2], o[3]);
        }
    }
}

__global__ __launch_bounds__(256) void egp_all_kernel(
    const float* __restrict__ h_base,
    const float* __restrict__ bias_e, const float* __restrict__ bias_h,
    const float* __restrict__ bias_t,
    const int* __restrict__ mask, float* __restrict__ out)
{
    __shared__ float qtT[64][68];
    __shared__ float kt [64][68];

    const int t   = threadIdx.x;
    const int m0  = blockIdx.x * 64;
    const int n0  = blockIdx.y * 64;
    const int fam = blockIdx.z >> 3;
    const int b   = blockIdx.z & 7;

    const size_t ent_sz  = (size_t)B_ * 2 * N_ * N_;
    const size_t head_sz = (size_t)B_ * 12 * N_ * N_;

    if (fam == 0) {
        egp_tile<2, true, true>(h_base, bias_e, mask, out, b, m0, n0, qtT, kt, t);
    } else if (fam == 1) {
        egp_tile<12, false, false>(h_base + (size_t)M_ * E_, bias_h, mask,
                                   out + ent_sz, b, m0, n0, qtT, kt, t);
    } else {
        egp_tile<12, false, false>(h_base + (size_t)2 * M_ * E_, bias_t, mask,
                                   out + ent_sz + head_sz, b, m0, n0, qtT, kt, t);
    }
}

// ---------------------------------------------------------------------------
extern "C" void kernel_launch(void* const* d_in, const int* in_sizes, int n_in,
                              void* d_out, int out_size, void* d_ws, size_t ws_size,
                              hipStream_t stream)
{
    const float* chars = (const float*)d_in[0];
    const int*   mask  = (const int*)d_in[1];
    const float* w1e = (const float*)d_in[2];
    const float* b1e = (const float*)d_in[3];
    const float* w2e = (const float*)d_in[4];
    const float* b2e = (const float*)d_in[5];
    const float* w1h = (const float*)d_in[6];
    const float* b1h = (const float*)d_in[7];
    const float* w2h = (const float*)d_in[8];
    const float* b2h = (const float*)d_in[9];
    const float* w1t = (const float*)d_in[10];
    const float* b1t = (const float*)d_in[11];
    const float* w2t = (const float*)d_in[12];
    const float* b2t = (const float*)d_in[13];

    float* out = (float*)d_out;

    float* h_ws   = (float*)d_ws;                       // 3 * 4096 * 128
    float* bias_e = h_ws + (size_t)3 * M_ * E_;         // 8*4*512
    float* bias_h = bias_e + (size_t)B_ * 4 * N_;       // 8*24*512
    float* bias_t = bias_h + (size_t)B_ * 24 * N_;      // 8*24*512

    prep_kernel<<<dim3(M_ / 32, 3), 256, 0, stream>>>(
        chars, w1e, b1e, w2e, b2e, w1h, b1h, w2h, b2h, w1t, b1t, w2t, b2t,
        h_ws, bias_e, bias_h, bias_t);

    egp_all_kernel<<<dim3(8, 8, 24), 256, 0, stream>>>(
        h_ws, bias_e, bias_h, bias_t, mask, out);
}

// Round 3
// 297.327 us; speedup vs baseline: 1.2403x; 1.0713x over previous
//
#include <hip/hip_runtime.h>
#include <cstddef>

namespace {
constexpr int B_ = 8;
constexpr int N_ = 512;
constexpr int D_ = 768;
constexpr int HS_ = 64;
constexpr int M_ = B_ * N_;   // 4096 rows (b*N + n)
constexpr int E_ = 2 * HS_;   // 128
constexpr float NEGV = 1000000000000.0f;
constexpr float LOG2_10000 = 13.287712379549449f;
}

typedef short mfrag_t __attribute__((ext_vector_type(8)));   // 8 bf16 (4 VGPRs)
typedef float macc_t  __attribute__((ext_vector_type(4)));   // 4 fp32

__device__ __forceinline__ unsigned short bft(float x) {
    union { float f; unsigned u; } c; c.f = x;
    return (unsigned short)(c.u >> 16);   // truncating fp32->bf16 (RTZ) — plenty accurate here
}

// ---------------------------------------------------------------------------
// Stage 1 (MFMA): h = chars @ w1^T + b1 ; bias = (h @ w2^T + b2)*0.5 fused.
// grid (64, 3), block 256 (4 waves). Tile M=64, N=128(all of E), KB=32.
// Each wave: 16-row strip x 128 cols = 8 mfma_f32_16x16x32_bf16 accumulators.
// A-frag: A[m=lane&15][k=quad*8+j]; B-frag: B[k=quad*8+j][n=lane&15] — both
// read as 16B contiguous from [row][k] LDS layouts (row stride 40 bf16 = 80B).
// ---------------------------------------------------------------------------
__global__ __launch_bounds__(256) void prep_kernel(
    const float* __restrict__ chars,
    const float* __restrict__ w1e, const float* __restrict__ b1e,
    const float* __restrict__ w2e, const float* __restrict__ b2e,
    const float* __restrict__ w1h, const float* __restrict__ b1h,
    const float* __restrict__ w2h, const float* __restrict__ b2h,
    const float* __restrict__ w1t, const float* __restrict__ b1t,
    const float* __restrict__ w2t, const float* __restrict__ b2t,
    float* __restrict__ h_base,
    float* __restrict__ bias_e, float* __restrict__ bias_h, float* __restrict__ bias_t)
{
    const int fam = blockIdx.y;
    const float* w1 = (fam == 0) ? w1e : (fam == 1) ? w1h : w1t;
    const float* b1 = (fam == 0) ? b1e : (fam == 1) ? b1h : b1t;
    const float* w2 = (fam == 0) ? w2e : (fam == 1) ? w2h : w2t;
    const float* b2 = (fam == 0) ? b2e : (fam == 1) ? b2h : b2t;
    float* bout = (fam == 0) ? bias_e : (fam == 1) ? bias_h : bias_t;
    const int H2 = (fam == 0) ? 4 : 24;
    float* hout = h_base + (size_t)fam * M_ * E_;
    const int m0 = blockIdx.x * 64;

    __shared__ unsigned short A_lds[64][40];    // [row][k], pad 32->40 (80B rows)
    __shared__ unsigned short B_lds[128][40];   // [col(n)][k]
    __shared__ float hs[64][132];               // h tile for fused bias + store

    const int t    = threadIdx.x;
    const int w    = t >> 6;          // wave 0..3 -> rows w*16..w*16+15
    const int lane = t & 63;
    const int ml   = lane & 15;
    const int quad = lane >> 4;

    // staging assignments
    const int ar = t >> 2;            // A row 0..63
    const int ak = (t & 3) * 8;       // A k-offset (8 floats)
    const int bc = t >> 1;            // B col 0..127
    const int bk = (t & 1) * 16;      // B k-offset (16 floats)

    const float* aptr = chars + (size_t)(m0 + ar) * D_ + ak;
    const float* bptr = w1 + (size_t)bc * D_ + bk;

    macc_t acc[8];
    #pragma unroll
    for (int f = 0; f < 8; ++f) acc[f] = (macc_t)0.0f;

    // prefetch step 0
    float4 av0 = *(const float4*)(aptr);
    float4 av1 = *(const float4*)(aptr + 4);
    float4 bv0 = *(const float4*)(bptr);
    float4 bv1 = *(const float4*)(bptr + 4);
    float4 bv2 = *(const float4*)(bptr + 8);
    float4 bv3 = *(const float4*)(bptr + 12);

    for (int s = 0; s < 24; ++s) {
        // commit staged regs to LDS (bf16)
        {
            mfrag_t pa;
            pa[0] = (short)bft(av0.x); pa[1] = (short)bft(av0.y);
            pa[2] = (short)bft(av0.z); pa[3] = (short)bft(av0.w);
            pa[4] = (short)bft(av1.x); pa[5] = (short)bft(av1.y);
            pa[6] = (short)bft(av1.z); pa[7] = (short)bft(av1.w);
            *(mfrag_t*)&A_lds[ar][ak] = pa;
            mfrag_t pb0, pb1;
            pb0[0] = (short)bft(bv0.x); pb0[1] = (short)bft(bv0.y);
            pb0[2] = (short)bft(bv0.z); pb0[3] = (short)bft(bv0.w);
            pb0[4] = (short)bft(bv1.x); pb0[5] = (short)bft(bv1.y);
            pb0[6] = (short)bft(bv1.z); pb0[7] = (short)bft(bv1.w);
            pb1[0] = (short)bft(bv2.x); pb1[1] = (short)bft(bv2.y);
            pb1[2] = (short)bft(bv2.z); pb1[3] = (short)bft(bv2.w);
            pb1[4] = (short)bft(bv3.x); pb1[5] = (short)bft(bv3.y);
            pb1[6] = (short)bft(bv3.z); pb1[7] = (short)bft(bv3.w);
            *(mfrag_t*)&B_lds[bc][bk]     = pb0;
            *(mfrag_t*)&B_lds[bc][bk + 8] = pb1;
        }
        __syncthreads();
        // prefetch next step (overlaps MFMA section)
        if (s < 23) {
            aptr += 32; bptr += 32;
            av0 = *(const float4*)(aptr);
            av1 = *(const float4*)(aptr + 4);
            bv0 = *(const float4*)(bptr);
            bv1 = *(const float4*)(bptr + 4);
            bv2 = *(const float4*)(bptr + 8);
            bv3 = *(const float4*)(bptr + 12);
        }
        const mfrag_t afrag = *(const mfrag_t*)&A_lds[w * 16 + ml][quad * 8];
        #pragma unroll
        for (int f = 0; f < 8; ++f) {
            const mfrag_t bfrag = *(const mfrag_t*)&B_lds[f * 16 + ml][quad * 8];
            acc[f] = __builtin_amdgcn_mfma_f32_16x16x32_bf16(afrag, bfrag, acc[f], 0, 0, 0);
        }
        __syncthreads();
    }

    // C layout: col = f*16 + (lane&15), row = w*16 + quad*4 + reg
    #pragma unroll
    for (int f = 0; f < 8; ++f) {
        const int col = f * 16 + ml;
        const float bb1 = b1[col];
        #pragma unroll
        for (int r = 0; r < 4; ++r)
            hs[w * 16 + quad * 4 + r][col] = acc[f][r] + bb1;
    }
    __syncthreads();

    // h tile -> global (coalesced float4)
    {
        const int row = t >> 2;
        const int c0  = (t & 3) * 32;
        float* hp = hout + (size_t)(m0 + row) * E_ + c0;
        #pragma unroll
        for (int q = 0; q < 8; ++q)
            *(float4*)(hp + 4 * q) = *(const float4*)&hs[row][c0 + 4 * q];
    }

    // fused bias: thread handles row = t&63, heads h2 = (t>>6) + 4p
    {
        const int row = t & 63;
        const int h2b = t >> 6;
        const int P   = H2 >> 2;            // 1 (ent) or 6 (head/tail)
        const int bb  = m0 >> 9;
        const int nb  = (m0 & 511) + row;
        float accv[6] = {0, 0, 0, 0, 0, 0};
        for (int e0 = 0; e0 < E_; e0 += 16) {
            float4 hv0 = *(const float4*)&hs[row][e0];
            float4 hv1 = *(const float4*)&hs[row][e0 + 4];
            float4 hv2 = *(const float4*)&hs[row][e0 + 8];
            float4 hv3 = *(const float4*)&hs[row][e0 + 12];
            for (int p = 0; p < P; ++p) {
                const float* wr = w2 + (size_t)(h2b + 4 * p) * E_ + e0;  // wave-uniform
                const float4 w0 = *(const float4*)(wr);
                const float4 w1v = *(const float4*)(wr + 4);
                const float4 w2v = *(const float4*)(wr + 8);
                const float4 w3v = *(const float4*)(wr + 12);
                accv[p] += hv0.x * w0.x + hv0.y * w0.y + hv0.z * w0.z + hv0.w * w0.w
                         + hv1.x * w1v.x + hv1.y * w1v.y + hv1.z * w1v.z + hv1.w * w1v.w
                         + hv2.x * w2v.x + hv2.y * w2v.y + hv2.z * w2v.z + hv2.w * w2v.w
                         + hv3.x * w3v.x + hv3.y * w3v.y + hv3.z * w3v.z + hv3.w * w3v.w;
            }
        }
        for (int p = 0; p < P; ++p) {
            const int h2 = h2b + 4 * p;
            bout[((size_t)bb * H2 + h2) * N_ + nb] = (accv[p] + b2[h2]) * 0.5f;
        }
    }
}

// ---------------------------------------------------------------------------
// Stage 2: fused QK^T + bias broadcast + masks + store; all 3 families.
// grid (8, 8, 24): (m-tile, n-tile, fam*8+b), block 256. 64x64 tile, K=64.
// ---------------------------------------------------------------------------
template <int H, bool ROPE, bool TRIL>
__device__ __forceinline__ void egp_tile(
    const float* __restrict__ hfam, const float* __restrict__ biasfam,
    const int* __restrict__ mask, float* __restrict__ out,
    int b, int m0, int n0, float (*qtT)[68], float (*kt)[68], int t)
{
    const int srow = t >> 2;   // 0..63
    const int sch  = t & 3;    // 0..3

    {
        const float* hq = hfam + (size_t)(b * N_ + m0 + srow) * E_;
        const float* hk = hfam + (size_t)(b * N_ + n0 + srow) * E_;
        #pragma unroll
        for (int jj = 0; jj < 8; ++jj) {
            const int i = sch + 4 * jj;   // rope pair index 0..31
            const float4 v = *(const float4*)(hq + 4 * i);  // q[2i],k[2i],q[2i+1],k[2i+1]
            const float4 w = *(const float4*)(hk + 4 * i);
            if (ROPE) {
                const float inv = exp2f(-(float)i * (LOG2_10000 / 32.0f));
                float sq, cq, sk, ck;
                sincosf((float)(m0 + srow) * inv, &sq, &cq);
                sincosf((float)(n0 + srow) * inv, &sk, &ck);
                qtT[2 * i + 0][srow] = v.x * cq - v.z * sq;
                qtT[2 * i + 1][srow] = v.z * cq + v.x * sq;
                kt [2 * i + 0][srow] = w.y * ck - w.w * sk;
                kt [2 * i + 1][srow] = w.w * ck + w.y * sk;
            } else {
                qtT[2 * i + 0][srow] = v.x;
                qtT[2 * i + 1][srow] = v.z;
                kt [2 * i + 0][srow] = w.y;
                kt [2 * i + 1][srow] = w.w;
            }
        }
    }
    __syncthreads();

    const int rq = t >> 4;   // 0..15 -> rows m0 + 4*rq + j
    const int cq = t & 15;   // 0..15 -> cols n0 + 4*cq + q

    float acc[4][4] = {};
    #pragma unroll 8
    for (int k = 0; k < 64; ++k) {
        const float4 av = *(const float4*)&qtT[k][4 * rq];
        const float4 kv = *(const float4*)&kt [k][4 * cq];
        acc[0][0] += av.x * kv.x; acc[0][1] += av.x * kv.y; acc[0][2] += av.x * kv.z; acc[0][3] += av.x * kv.w;
        acc[1][0] += av.y * kv.x; acc[1][1] += av.y * kv.y; acc[1][2] += av.y * kv.z; acc[1][3] += av.y * kv.w;
        acc[2][0] += av.z * kv.x; acc[2][1] += av.z * kv.y; acc[2][2] += av.z * kv.z; acc[2][3] += av.z * kv.w;
        acc[3][0] += av.w * kv.x; acc[3][1] += av.w * kv.y; acc[3][2] += av.w * kv.z; acc[3][3] += av.w * kv.w;
    }

    #pragma unroll
    for (int j = 0; j < 4; ++j)
        #pragma unroll
        for (int q = 0; q < 4; ++q) acc[j][q] *= 0.125f;   // 1/sqrt(64)

    int mrow[4], mm[4];
    #pragma unroll
    for (int j = 0; j < 4; ++j) {
        mrow[j] = m0 + 4 * rq + j;
        mm[j]   = mask[b * N_ + mrow[j]];
    }
    const int ncol = n0 + 4 * cq;
    const int4 mnv = *(const int4*)(mask + b * N_ + ncol);
    const int mn[4] = { mnv.x, mnv.y, mnv.z, mnv.w };

    #pragma unroll
    for (int hh = 0; hh < H; ++hh) {
        const float4 be = *(const float4*)(biasfam + ((size_t)b * 2 * H + 2 * hh) * N_ + ncol);
        float bo[4];
        #pragma unroll
        for (int j = 0; j < 4; ++j)
            bo[j] = biasfam[((size_t)b * 2 * H + 2 * hh + 1) * N_ + mrow[j]];

        #pragma unroll
        for (int j = 0; j < 4; ++j) {
            float o[4] = { acc[j][0] + be.x + bo[j], acc[j][1] + be.y + bo[j],
                           acc[j][2] + be.z + bo[j], acc[j][3] + be.w + bo[j] };
            #pragma unroll
            for (int q = 0; q < 4; ++q) {
                if (!(mm[j] & mn[q])) o[q] -= NEGV;
                if (TRIL && (ncol + q) < mrow[j]) o[q] -= NEGV;
            }
            *(float4*)(out + ((size_t)(b * H + hh) * N_ + mrow[j]) * N_ + ncol) =
                make_float4(o[0], o[1], o[2], o[3]);
        }
    }
}

__global__ __launch_bounds__(256) void egp_all_kernel(
    const float* __restrict__ h_base,
    const float* __restrict__ bias_e, const float* __restrict__ bias_h,
    const float* __restrict__ bias_t,
    const int* __restrict__ mask, float* __restrict__ out)
{
    __shared__ float qtT[64][68];
    __shared__ float kt [64][68];

    const int t   = threadIdx.x;
    const int m0  = blockIdx.x * 64;
    const int n0  = blockIdx.y * 64;
    const int fam = blockIdx.z >> 3;
    const int b   = blockIdx.z & 7;

    const size_t ent_sz  = (size_t)B_ * 2 * N_ * N_;
    const size_t head_sz = (size_t)B_ * 12 * N_ * N_;

    if (fam == 0) {
        egp_tile<2, true, true>(h_base, bias_e, mask, out, b, m0, n0, qtT, kt, t);
    } else if (fam == 1) {
        egp_tile<12, false, false>(h_base + (size_t)M_ * E_, bias_h, mask,
                                   out + ent_sz, b, m0, n0, qtT, kt, t);
    } else {
        egp_tile<12, false, false>(h_base + (size_t)2 * M_ * E_, bias_t, mask,
                                   out + ent_sz + head_sz, b, m0, n0, qtT, kt, t);
    }
}

// ---------------------------------------------------------------------------
extern "C" void kernel_launch(void* const* d_in, const int* in_sizes, int n_in,
                              void* d_out, int out_size, void* d_ws, size_t ws_size,
                              hipStream_t stream)
{
    const float* chars = (const float*)d_in[0];
    const int*   mask  = (const int*)d_in[1];
    const float* w1e = (const float*)d_in[2];
    const float* b1e = (const float*)d_in[3];
    const float* w2e = (const float*)d_in[4];
    const float* b2e = (const float*)d_in[5];
    const float* w1h = (const float*)d_in[6];
    const float* b1h = (const float*)d_in[7];
    const float* w2h = (const float*)d_in[8];
    const float* b2h = (const float*)d_in[9];
    const float* w1t = (const float*)d_in[10];
    const float* b1t = (const float*)d_in[11];
    const float* w2t = (const float*)d_in[12];
    const float* b2t = (const float*)d_in[13];

    float* out = (float*)d_out;

    float* h_ws   = (float*)d_ws;                       // 3 * 4096 * 128
    float* bias_e = h_ws + (size_t)3 * M_ * E_;         // 8*4*512
    float* bias_h = bias_e + (size_t)B_ * 4 * N_;       // 8*24*512
    float* bias_t = bias_h + (size_t)B_ * 24 * N_;      // 8*24*512

    prep_kernel<<<dim3(64, 3), 256, 0, stream>>>(
        chars, w1e, b1e, w2e, b2e, w1h, b1h, w2h, b2h, w1t, b1t, w2t, b2t,
        h_ws, bias_e, bias_h, bias_t);

    egp_all_kernel<<<dim3(8, 8, 24), 256, 0, stream>>>(
        h_ws, bias_e, bias_h, bias_t, mask, out);
}

// Round 4
// 283.945 us; speedup vs baseline: 1.2988x; 1.0471x over previous
//
#include <hip/hip_runtime.h>
#include <cstddef>

namespace {
constexpr int B_ = 8;
constexpr int N_ = 512;
constexpr int D_ = 768;
constexpr int HS_ = 64;
constexpr int M_ = B_ * N_;   // 4096 rows (b*N + n)
constexpr int E_ = 2 * HS_;   // 128
constexpr float NEGV = 1000000000000.0f;
constexpr float LOG2_10000 = 13.287712379549449f;
}

typedef short mfrag_t __attribute__((ext_vector_type(8)));   // 8 bf16 (4 VGPRs)
typedef float macc_t  __attribute__((ext_vector_type(4)));   // 4 fp32

__device__ __forceinline__ unsigned short bft(float x) {
    union { float f; unsigned u; } c; c.f = x;
    return (unsigned short)(c.u >> 16);   // truncate (RTZ)
}
__device__ __forceinline__ unsigned short bfrne(float x) {
    union { float f; unsigned u; } c; c.f = x;
    const unsigned r = c.u + 0x7FFFu + ((c.u >> 16) & 1u);
    return (unsigned short)(r >> 16);     // round-to-nearest-even
}

// ---------------------------------------------------------------------------
// Stage 1 (MFMA): h = chars @ w1^T + b1 (kept in LDS only);
//   bias = (h @ w2^T + b2)*0.5  (fused);
//   qbf/kbf = roped bf16 q/k in [row][k] fragment-ready layout.
// grid (64, 3), block 256 (4 waves). Tile M=64, N=128(all of E), KB=32.
// ---------------------------------------------------------------------------
__global__ __launch_bounds__(256) void prep_kernel(
    const float* __restrict__ chars,
    const float* __restrict__ w1e, const float* __restrict__ b1e,
    const float* __restrict__ w2e, const float* __restrict__ b2e,
    const float* __restrict__ w1h, const float* __restrict__ b1h,
    const float* __restrict__ w2h, const float* __restrict__ b2h,
    const float* __restrict__ w1t, const float* __restrict__ b1t,
    const float* __restrict__ w2t, const float* __restrict__ b2t,
    unsigned short* __restrict__ qbf, unsigned short* __restrict__ kbf,
    float* __restrict__ bias_e, float* __restrict__ bias_h, float* __restrict__ bias_t)
{
    const int fam = blockIdx.y;
    const float* w1 = (fam == 0) ? w1e : (fam == 1) ? w1h : w1t;
    const float* b1 = (fam == 0) ? b1e : (fam == 1) ? b1h : b1t;
    const float* w2 = (fam == 0) ? w2e : (fam == 1) ? w2h : w2t;
    const float* b2 = (fam == 0) ? b2e : (fam == 1) ? b2h : b2t;
    float* bout = (fam == 0) ? bias_e : (fam == 1) ? bias_h : bias_t;
    const int H2 = (fam == 0) ? 4 : 24;
    unsigned short* qout = qbf + (size_t)fam * M_ * HS_;
    unsigned short* kout = kbf + (size_t)fam * M_ * HS_;
    const int m0 = blockIdx.x * 64;

    __shared__ unsigned short A_lds[64][40];    // [row][k], pad 32->40 (80B rows)
    __shared__ unsigned short B_lds[128][40];   // [col(n)][k]
    __shared__ float hs[64][132];               // h tile for fused outputs

    const int t    = threadIdx.x;
    const int w    = t >> 6;          // wave 0..3 -> rows w*16..w*16+15
    const int lane = t & 63;
    const int ml   = lane & 15;
    const int quad = lane >> 4;

    const int ar = t >> 2;            // A row 0..63
    const int ak = (t & 3) * 8;       // A k-offset (8 floats)
    const int bc = t >> 1;            // B col 0..127
    const int bk = (t & 1) * 16;      // B k-offset (16 floats)

    const float* aptr = chars + (size_t)(m0 + ar) * D_ + ak;
    const float* bptr = w1 + (size_t)bc * D_ + bk;

    macc_t acc[8];
    #pragma unroll
    for (int f = 0; f < 8; ++f) acc[f] = (macc_t)0.0f;

    float4 av0 = *(const float4*)(aptr);
    float4 av1 = *(const float4*)(aptr + 4);
    float4 bv0 = *(const float4*)(bptr);
    float4 bv1 = *(const float4*)(bptr + 4);
    float4 bv2 = *(const float4*)(bptr + 8);
    float4 bv3 = *(const float4*)(bptr + 12);

    for (int s = 0; s < 24; ++s) {
        {
            mfrag_t pa;
            pa[0] = (short)bft(av0.x); pa[1] = (short)bft(av0.y);
            pa[2] = (short)bft(av0.z); pa[3] = (short)bft(av0.w);
            pa[4] = (short)bft(av1.x); pa[5] = (short)bft(av1.y);
            pa[6] = (short)bft(av1.z); pa[7] = (short)bft(av1.w);
            *(mfrag_t*)&A_lds[ar][ak] = pa;
            mfrag_t pb0, pb1;
            pb0[0] = (short)bft(bv0.x); pb0[1] = (short)bft(bv0.y);
            pb0[2] = (short)bft(bv0.z); pb0[3] = (short)bft(bv0.w);
            pb0[4] = (short)bft(bv1.x); pb0[5] = (short)bft(bv1.y);
            pb0[6] = (short)bft(bv1.z); pb0[7] = (short)bft(bv1.w);
            pb1[0] = (short)bft(bv2.x); pb1[1] = (short)bft(bv2.y);
            pb1[2] = (short)bft(bv2.z); pb1[3] = (short)bft(bv2.w);
            pb1[4] = (short)bft(bv3.x); pb1[5] = (short)bft(bv3.y);
            pb1[6] = (short)bft(bv3.z); pb1[7] = (short)bft(bv3.w);
            *(mfrag_t*)&B_lds[bc][bk]     = pb0;
            *(mfrag_t*)&B_lds[bc][bk + 8] = pb1;
        }
        __syncthreads();
        if (s < 23) {
            aptr += 32; bptr += 32;
            av0 = *(const float4*)(aptr);
            av1 = *(const float4*)(aptr + 4);
            bv0 = *(const float4*)(bptr);
            bv1 = *(const float4*)(bptr + 4);
            bv2 = *(const float4*)(bptr + 8);
            bv3 = *(const float4*)(bptr + 12);
        }
        const mfrag_t afrag = *(const mfrag_t*)&A_lds[w * 16 + ml][quad * 8];
        #pragma unroll
        for (int f = 0; f < 8; ++f) {
            const mfrag_t bfrag = *(const mfrag_t*)&B_lds[f * 16 + ml][quad * 8];
            acc[f] = __builtin_amdgcn_mfma_f32_16x16x32_bf16(afrag, bfrag, acc[f], 0, 0, 0);
        }
        __syncthreads();
    }

    // C layout: col = f*16 + ml, row = w*16 + quad*4 + r
    #pragma unroll
    for (int f = 0; f < 8; ++f) {
        const int col = f * 16 + ml;
        const float bb1 = b1[col];
        #pragma unroll
        for (int r = 0; r < 4; ++r)
            hs[w * 16 + quad * 4 + r][col] = acc[f][r] + bb1;
    }
    __syncthreads();

    // q/k extraction (+rope for fam 0) -> bf16 [row][k] fragment layout.
    // q[j] = h[2j], k[j] = h[2j+1]; rope pairs (q[2i],q[2i+1]) etc.
    {
        const int row = t >> 2;          // 0..63
        const int kg  = t & 3;           // 16 k-values per thread
        const float pos = (float)((m0 & 511) + row);
        unsigned short qv[16], kv[16];
        #pragma unroll
        for (int p = 0; p < 8; ++p) {
            const int i = kg * 8 + p;    // pair index 0..31
            const float q0 = hs[row][4 * i + 0];
            const float k0 = hs[row][4 * i + 1];
            const float q1 = hs[row][4 * i + 2];
            const float k1 = hs[row][4 * i + 3];
            if (fam == 0) {
                const float inv = exp2f(-(float)i * (LOG2_10000 / 32.0f));
                float sn, cs;
                sincosf(pos * inv, &sn, &cs);
                qv[2 * p + 0] = bfrne(q0 * cs - q1 * sn);
                qv[2 * p + 1] = bfrne(q1 * cs + q0 * sn);
                kv[2 * p + 0] = bfrne(k0 * cs - k1 * sn);
                kv[2 * p + 1] = bfrne(k1 * cs + k0 * sn);
            } else {
                qv[2 * p + 0] = bfrne(q0);
                qv[2 * p + 1] = bfrne(q1);
                kv[2 * p + 0] = bfrne(k0);
                kv[2 * p + 1] = bfrne(k1);
            }
        }
        unsigned short* qp = qout + (size_t)(m0 + row) * HS_ + kg * 16;
        unsigned short* kp = kout + (size_t)(m0 + row) * HS_ + kg * 16;
        *(mfrag_t*)qp       = *(const mfrag_t*)&qv[0];
        *(mfrag_t*)(qp + 8) = *(const mfrag_t*)&qv[8];
        *(mfrag_t*)kp       = *(const mfrag_t*)&kv[0];
        *(mfrag_t*)(kp + 8) = *(const mfrag_t*)&kv[8];
    }

    // fused bias: thread handles row = t&63, heads h2 = (t>>6) + 4p
    {
        const int row = t & 63;
        const int h2b = t >> 6;
        const int P   = H2 >> 2;
        const int bb  = m0 >> 9;
        const int nb  = (m0 & 511) + row;
        float accv[6] = {0, 0, 0, 0, 0, 0};
        for (int e0 = 0; e0 < E_; e0 += 16) {
            float4 hv0 = *(const float4*)&hs[row][e0];
            float4 hv1 = *(const float4*)&hs[row][e0 + 4];
            float4 hv2 = *(const float4*)&hs[row][e0 + 8];
            float4 hv3 = *(const float4*)&hs[row][e0 + 12];
            for (int p = 0; p < P; ++p) {
                const float* wr = w2 + (size_t)(h2b + 4 * p) * E_ + e0;  // wave-uniform
                const float4 w0 = *(const float4*)(wr);
                const float4 w1v = *(const float4*)(wr + 4);
                const float4 w2v = *(const float4*)(wr + 8);
                const float4 w3v = *(const float4*)(wr + 12);
                accv[p] += hv0.x * w0.x + hv0.y * w0.y + hv0.z * w0.z + hv0.w * w0.w
                         + hv1.x * w1v.x + hv1.y * w1v.y + hv1.z * w1v.z + hv1.w * w1v.w
                         + hv2.x * w2v.x + hv2.y * w2v.y + hv2.z * w2v.z + hv2.w * w2v.w
                         + hv3.x * w3v.x + hv3.y * w3v.y + hv3.z * w3v.z + hv3.w * w3v.w;
            }
        }
        for (int p = 0; p < P; ++p) {
            const int h2 = h2b + 4 * p;
            bout[((size_t)bb * H2 + h2) * N_ + nb] = (accv[p] + b2[h2]) * 0.5f;
        }
    }
}

// ---------------------------------------------------------------------------
// Stage 2: MFMA QK^T (fragments direct from global bf16 q/k) + bias + masks.
// grid (8, 8, 24): (m-tile, n-tile, fam*8+b), block 256. 64x64 tile, K=64.
// ---------------------------------------------------------------------------
template <int H, bool TRIL>
__device__ __forceinline__ void egp_tile(
    const unsigned short* __restrict__ qf, const unsigned short* __restrict__ kf,
    const float* __restrict__ biasfam, const int* __restrict__ mask,
    float* __restrict__ out, int b, int m0, int n0, float (*Cs)[68], int t)
{
    const int w    = t >> 6;
    const int lane = t & 63;
    const int ml   = lane & 15;
    const int quad = lane >> 4;

    macc_t acc[4];
    #pragma unroll
    for (int f = 0; f < 4; ++f) acc[f] = (macc_t)0.0f;

    const unsigned short* qrow = qf + (size_t)(b * N_ + m0 + w * 16 + ml) * HS_ + quad * 8;
    const unsigned short* krow = kf + (size_t)(b * N_ + n0 + ml) * HS_ + quad * 8;

    #pragma unroll
    for (int s = 0; s < 2; ++s) {
        const mfrag_t af = *(const mfrag_t*)(qrow + s * 32);
        #pragma unroll
        for (int f = 0; f < 4; ++f) {
            const mfrag_t bf = *(const mfrag_t*)(krow + (size_t)f * 16 * HS_ + s * 32);
            acc[f] = __builtin_amdgcn_mfma_f32_16x16x32_bf16(af, bf, acc[f], 0, 0, 0);
        }
    }

    // C layout -> LDS: row = w*16 + quad*4 + r, col = f*16 + ml  (scaled)
    #pragma unroll
    for (int f = 0; f < 4; ++f)
        #pragma unroll
        for (int r = 0; r < 4; ++r)
            Cs[w * 16 + quad * 4 + r][f * 16 + ml] = acc[f][r] * 0.125f;
    __syncthreads();

    const int rq = t >> 4;   // rows m0 + 4*rq + j
    const int cq = t & 15;   // cols n0 + 4*cq + q

    float4 av[4];
    #pragma unroll
    for (int j = 0; j < 4; ++j) av[j] = *(const float4*)&Cs[4 * rq + j][4 * cq];

    int mrow[4], mm[4];
    #pragma unroll
    for (int j = 0; j < 4; ++j) {
        mrow[j] = m0 + 4 * rq + j;
        mm[j]   = mask[b * N_ + mrow[j]];
    }
    const int ncol = n0 + 4 * cq;
    const int4 mnv = *(const int4*)(mask + b * N_ + ncol);
    const int mn[4] = { mnv.x, mnv.y, mnv.z, mnv.w };

    #pragma unroll
    for (int hh = 0; hh < H; ++hh) {
        const float4 be = *(const float4*)(biasfam + ((size_t)b * 2 * H + 2 * hh) * N_ + ncol);
        float bo[4];
        #pragma unroll
        for (int j = 0; j < 4; ++j)
            bo[j] = biasfam[((size_t)b * 2 * H + 2 * hh + 1) * N_ + mrow[j]];

        #pragma unroll
        for (int j = 0; j < 4; ++j) {
            const float* aj = (const float*)&av[j];
            float o[4] = { aj[0] + be.x + bo[j], aj[1] + be.y + bo[j],
                           aj[2] + be.z + bo[j], aj[3] + be.w + bo[j] };
            #pragma unroll
            for (int q = 0; q < 4; ++q) {
                if (!(mm[j] & mn[q])) o[q] -= NEGV;
                if (TRIL && (ncol + q) < mrow[j]) o[q] -= NEGV;
            }
            *(float4*)(out + ((size_t)(b * H + hh) * N_ + mrow[j]) * N_ + ncol) =
                make_float4(o[0], o[1], o[2], o[3]);
        }
    }
}

__global__ __launch_bounds__(256) void egp_all_kernel(
    const unsigned short* __restrict__ qbf, const unsigned short* __restrict__ kbf,
    const float* __restrict__ bias_e, const float* __restrict__ bias_h,
    const float* __restrict__ bias_t,
    const int* __restrict__ mask, float* __restrict__ out)
{
    __shared__ float Cs[64][68];

    const int t   = threadIdx.x;
    const int m0  = blockIdx.x * 64;
    const int n0  = blockIdx.y * 64;
    const int fam = blockIdx.z >> 3;
    const int b   = blockIdx.z & 7;

    const size_t ent_sz  = (size_t)B_ * 2 * N_ * N_;
    const size_t head_sz = (size_t)B_ * 12 * N_ * N_;
    const size_t fsl = (size_t)M_ * HS_;

    if (fam == 0) {
        egp_tile<2, true>(qbf, kbf, bias_e, mask, out, b, m0, n0, Cs, t);
    } else if (fam == 1) {
        egp_tile<12, false>(qbf + fsl, kbf + fsl, bias_h, mask,
                            out + ent_sz, b, m0, n0, Cs, t);
    } else {
        egp_tile<12, false>(qbf + 2 * fsl, kbf + 2 * fsl, bias_t, mask,
                            out + ent_sz + head_sz, b, m0, n0, Cs, t);
    }
}

// ---------------------------------------------------------------------------
extern "C" void kernel_launch(void* const* d_in, const int* in_sizes, int n_in,
                              void* d_out, int out_size, void* d_ws, size_t ws_size,
                              hipStream_t stream)
{
    const float* chars = (const float*)d_in[0];
    const int*   mask  = (const int*)d_in[1];
    const float* w1e = (const float*)d_in[2];
    const float* b1e = (const float*)d_in[3];
    const float* w2e = (const float*)d_in[4];
    const float* b2e = (const float*)d_in[5];
    const float* w1h = (const float*)d_in[6];
    const float* b1h = (const float*)d_in[7];
    const float* w2h = (const float*)d_in[8];
    const float* b2h = (const float*)d_in[9];
    const float* w1t = (const float*)d_in[10];
    const float* b1t = (const float*)d_in[11];
    const float* w2t = (const float*)d_in[12];
    const float* b2t = (const float*)d_in[13];

    float* out = (float*)d_out;

    // workspace layout
    unsigned short* qbf = (unsigned short*)d_ws;               // 3*4096*64 bf16
    unsigned short* kbf = qbf + (size_t)3 * M_ * HS_;          // 3*4096*64 bf16
    float* bias_e = (float*)(kbf + (size_t)3 * M_ * HS_);      // 8*4*512
    float* bias_h = bias_e + (size_t)B_ * 4 * N_;              // 8*24*512
    float* bias_t = bias_h + (size_t)B_ * 24 * N_;             // 8*24*512

    prep_kernel<<<dim3(64, 3), 256, 0, stream>>>(
        chars, w1e, b1e, w2e, b2e, w1h, b1h, w2h, b2h, w1t, b1t, w2t, b2t,
        qbf, kbf, bias_e, bias_h, bias_t);

    egp_all_kernel<<<dim3(8, 8, 24), 256, 0, stream>>>(
        qbf, kbf, bias_e, bias_h, bias_t, mask, out);
}

// Round 6
// 283.121 us; speedup vs baseline: 1.3026x; 1.0029x over previous
//
#include <hip/hip_runtime.h>
#include <cstddef>

namespace {
constexpr int B_ = 8;
constexpr int N_ = 512;
constexpr int D_ = 768;
constexpr int HS_ = 64;
constexpr int M_ = B_ * N_;   // 4096 rows (b*N + n)
constexpr int E_ = 2 * HS_;   // 128
constexpr float NEGV = 1000000000000.0f;
constexpr float LOG2_10000 = 13.287712379549449f;
}

typedef short mfrag_t __attribute__((ext_vector_type(8)));   // 8 bf16 (4 VGPRs)
typedef short mhalf_t __attribute__((ext_vector_type(4)));   // 4 bf16 (2 VGPRs)
typedef float macc_t  __attribute__((ext_vector_type(4)));   // 4 fp32
typedef float vf4_t   __attribute__((ext_vector_type(4)));   // clang vector for nt-store

__device__ __forceinline__ unsigned short bft(float x) {
    union { float f; unsigned u; } c; c.f = x;
    return (unsigned short)(c.u >> 16);   // truncate (RTZ)
}
__device__ __forceinline__ unsigned short bfrne(float x) {
    union { float f; unsigned u; } c; c.f = x;
    const unsigned r = c.u + 0x7FFFu + ((c.u >> 16) & 1u);
    return (unsigned short)(r >> 16);     // round-to-nearest-even
}

// ---------------------------------------------------------------------------
// Stage 1 (MFMA): h = chars @ w1^T + b1 (LDS only);
//   bias = (h @ w2^T + b2)*0.5  (fused);
//   qbf/kbf = roped bf16 q/k in [row][k] fragment-ready layout.
// grid (128, 3), block 256 (4 waves). Tile M=32, N=128(all of E), KB=32.
// Wave w: rows (w&1)*16, col-half (w>>1)*64; 4 accumulators each.
// ---------------------------------------------------------------------------
__global__ __launch_bounds__(256) void prep_kernel(
    const float* __restrict__ chars,
    const float* __restrict__ w1e, const float* __restrict__ b1e,
    const float* __restrict__ w2e, const float* __restrict__ b2e,
    const float* __restrict__ w1h, const float* __restrict__ b1h,
    const float* __restrict__ w2h, const float* __restrict__ b2h,
    const float* __restrict__ w1t, const float* __restrict__ b1t,
    const float* __restrict__ w2t, const float* __restrict__ b2t,
    unsigned short* __restrict__ qbf, unsigned short* __restrict__ kbf,
    float* __restrict__ bias_e, float* __restrict__ bias_h, float* __restrict__ bias_t)
{
    const int fam = blockIdx.y;
    const float* w1 = (fam == 0) ? w1e : (fam == 1) ? w1h : w1t;
    const float* b1 = (fam == 0) ? b1e : (fam == 1) ? b1h : b1t;
    const float* w2 = (fam == 0) ? w2e : (fam == 1) ? w2h : w2t;
    const float* b2 = (fam == 0) ? b2e : (fam == 1) ? b2h : b2t;
    float* bout = (fam == 0) ? bias_e : (fam == 1) ? bias_h : bias_t;
    const int H2 = (fam == 0) ? 4 : 24;
    unsigned short* qout = qbf + (size_t)fam * M_ * HS_;
    unsigned short* kout = kbf + (size_t)fam * M_ * HS_;
    const int m0 = blockIdx.x * 32;

    __shared__ unsigned short A_lds[32][40];    // [row][k], pad 32->40 (80B rows)
    __shared__ unsigned short B_lds[128][40];   // [col(n)][k]
    __shared__ float hs[32][132];               // h tile for fused outputs

    const int t    = threadIdx.x;
    const int w    = t >> 6;          // wave 0..3
    const int lane = t & 63;
    const int ml   = lane & 15;
    const int quad = lane >> 4;
    const int wr16 = (w & 1) * 16;    // wave row strip
    const int wc64 = (w >> 1) * 64;   // wave col half

    const int ar = t >> 3;            // A row 0..31
    const int ak = (t & 7) * 4;       // A k-offset (4 floats)
    const int bc = t >> 1;            // B col 0..127
    const int bk = (t & 1) * 16;      // B k-offset (16 floats)

    const float* aptr = chars + (size_t)(m0 + ar) * D_ + ak;
    const float* bptr = w1 + (size_t)bc * D_ + bk;

    macc_t acc[4];
    #pragma unroll
    for (int f = 0; f < 4; ++f) acc[f] = (macc_t)0.0f;

    float4 av0 = *(const float4*)(aptr);
    float4 bv0 = *(const float4*)(bptr);
    float4 bv1 = *(const float4*)(bptr + 4);
    float4 bv2 = *(const float4*)(bptr + 8);
    float4 bv3 = *(const float4*)(bptr + 12);

    for (int s = 0; s < 24; ++s) {
        {
            mhalf_t pa;
            pa[0] = (short)bft(av0.x); pa[1] = (short)bft(av0.y);
            pa[2] = (short)bft(av0.z); pa[3] = (short)bft(av0.w);
            *(mhalf_t*)&A_lds[ar][ak] = pa;
            mfrag_t pb0, pb1;
            pb0[0] = (short)bft(bv0.x); pb0[1] = (short)bft(bv0.y);
            pb0[2] = (short)bft(bv0.z); pb0[3] = (short)bft(bv0.w);
            pb0[4] = (short)bft(bv1.x); pb0[5] = (short)bft(bv1.y);
            pb0[6] = (short)bft(bv1.z); pb0[7] = (short)bft(bv1.w);
            pb1[0] = (short)bft(bv2.x); pb1[1] = (short)bft(bv2.y);
            pb1[2] = (short)bft(bv2.z); pb1[3] = (short)bft(bv2.w);
            pb1[4] = (short)bft(bv3.x); pb1[5] = (short)bft(bv3.y);
            pb1[6] = (short)bft(bv3.z); pb1[7] = (short)bft(bv3.w);
            *(mfrag_t*)&B_lds[bc][bk]     = pb0;
            *(mfrag_t*)&B_lds[bc][bk + 8] = pb1;
        }
        __syncthreads();
        if (s < 23) {
            aptr += 32; bptr += 32;
            av0 = *(const float4*)(aptr);
            bv0 = *(const float4*)(bptr);
            bv1 = *(const float4*)(bptr + 4);
            bv2 = *(const float4*)(bptr + 8);
            bv3 = *(const float4*)(bptr + 12);
        }
        const mfrag_t afrag = *(const mfrag_t*)&A_lds[wr16 + ml][quad * 8];
        #pragma unroll
        for (int f = 0; f < 4; ++f) {
            const mfrag_t bfrag = *(const mfrag_t*)&B_lds[wc64 + f * 16 + ml][quad * 8];
            acc[f] = __builtin_amdgcn_mfma_f32_16x16x32_bf16(afrag, bfrag, acc[f], 0, 0, 0);
        }
        __syncthreads();
    }

    // C layout: col = wc64 + f*16 + ml, row = wr16 + quad*4 + r
    #pragma unroll
    for (int f = 0; f < 4; ++f) {
        const int col = wc64 + f * 16 + ml;
        const float bb1 = b1[col];
        #pragma unroll
        for (int r = 0; r < 4; ++r)
            hs[wr16 + quad * 4 + r][col] = acc[f][r] + bb1;
    }
    __syncthreads();

    // q/k extraction (+rope for fam 0) -> bf16 [row][k] fragment layout.
    // q[j] = h[2j], k[j] = h[2j+1]; rope pairs (q[2i],q[2i+1]) etc.
    {
        const int row = t >> 3;          // 0..31
        const int kg  = t & 7;           // 8 k-values per thread
        const float pos = (float)((m0 & 511) + row);
        unsigned short qv[8], kv[8];
        #pragma unroll
        for (int p = 0; p < 4; ++p) {
            const int i = kg * 4 + p;    // pair index 0..31
            const float q0 = hs[row][4 * i + 0];
            const float k0 = hs[row][4 * i + 1];
            const float q1 = hs[row][4 * i + 2];
            const float k1 = hs[row][4 * i + 3];
            if (fam == 0) {
                const float inv = exp2f(-(float)i * (LOG2_10000 / 32.0f));
                float sn, cs;
                sincosf(pos * inv, &sn, &cs);
                qv[2 * p + 0] = bfrne(q0 * cs - q1 * sn);
                qv[2 * p + 1] = bfrne(q1 * cs + q0 * sn);
                kv[2 * p + 0] = bfrne(k0 * cs - k1 * sn);
                kv[2 * p + 1] = bfrne(k1 * cs + k0 * sn);
            } else {
                qv[2 * p + 0] = bfrne(q0);
                qv[2 * p + 1] = bfrne(q1);
                kv[2 * p + 0] = bfrne(k0);
                kv[2 * p + 1] = bfrne(k1);
            }
        }
        unsigned short* qp = qout + (size_t)(m0 + row) * HS_ + kg * 8;
        unsigned short* kp = kout + (size_t)(m0 + row) * HS_ + kg * 8;
        *(mfrag_t*)qp = *(const mfrag_t*)&qv[0];
        *(mfrag_t*)kp = *(const mfrag_t*)&kv[0];
    }

    // fused bias: thread handles row = t&31, heads h2 = (t>>5) + 8p
    {
        const int row = t & 31;
        const int h2b = t >> 5;          // 0..7
        const int bb  = m0 >> 9;
        const int nb  = (m0 & 511) + row;
        float accv[3] = {0, 0, 0};
        for (int e0 = 0; e0 < E_; e0 += 16) {
            float4 hv0 = *(const float4*)&hs[row][e0];
            float4 hv1 = *(const float4*)&hs[row][e0 + 4];
            float4 hv2 = *(const float4*)&hs[row][e0 + 8];
            float4 hv3 = *(const float4*)&hs[row][e0 + 12];
            int p = 0;
            for (int h2 = h2b; h2 < H2; h2 += 8, ++p) {
                const float* wr = w2 + (size_t)h2 * E_ + e0;
                const float4 w0 = *(const float4*)(wr);
                const float4 w1v = *(const float4*)(wr + 4);
                const float4 w2v = *(const float4*)(wr + 8);
                const float4 w3v = *(const float4*)(wr + 12);
                accv[p] += hv0.x * w0.x + hv0.y * w0.y + hv0.z * w0.z + hv0.w * w0.w
                         + hv1.x * w1v.x + hv1.y * w1v.y + hv1.z * w1v.z + hv1.w * w1v.w
                         + hv2.x * w2v.x + hv2.y * w2v.y + hv2.z * w2v.z + hv2.w * w2v.w
                         + hv3.x * w3v.x + hv3.y * w3v.y + hv3.z * w3v.z + hv3.w * w3v.w;
            }
        }
        int p = 0;
        for (int h2 = h2b; h2 < H2; h2 += 8, ++p)
            bout[((size_t)bb * H2 + h2) * N_ + nb] = (accv[p] + b2[h2]) * 0.5f;
    }
}

// ---------------------------------------------------------------------------
// Stage 2: MFMA QK^T (fragments direct from global bf16 q/k) + bias + masks.
// grid (8, 8, 24): (m-tile, n-tile, fam*8+b), block 256. 64x64 tile, K=64.
// Output stores are non-temporal (write-once stream, bypass L2 allocate).
// ---------------------------------------------------------------------------
template <int H, bool TRIL>
__device__ __forceinline__ void egp_tile(
    const unsigned short* __restrict__ qf, const unsigned short* __restrict__ kf,
    const float* __restrict__ biasfam, const int* __restrict__ mask,
    float* __restrict__ out, int b, int m0, int n0, float (*Cs)[68], int t)
{
    const int w    = t >> 6;
    const int lane = t & 63;
    const int ml   = lane & 15;
    const int quad = lane >> 4;

    macc_t acc[4];
    #pragma unroll
    for (int f = 0; f < 4; ++f) acc[f] = (macc_t)0.0f;

    const unsigned short* qrow = qf + (size_t)(b * N_ + m0 + w * 16 + ml) * HS_ + quad * 8;
    const unsigned short* krow = kf + (size_t)(b * N_ + n0 + ml) * HS_ + quad * 8;

    #pragma unroll
    for (int s = 0; s < 2; ++s) {
        const mfrag_t af = *(const mfrag_t*)(qrow + s * 32);
        #pragma unroll
        for (int f = 0; f < 4; ++f) {
            const mfrag_t bf = *(const mfrag_t*)(krow + (size_t)f * 16 * HS_ + s * 32);
            acc[f] = __builtin_amdgcn_mfma_f32_16x16x32_bf16(af, bf, acc[f], 0, 0, 0);
        }
    }

    // C layout -> LDS: row = w*16 + quad*4 + r, col = f*16 + ml  (scaled)
    #pragma unroll
    for (int f = 0; f < 4; ++f)
        #pragma unroll
        for (int r = 0; r < 4; ++r)
            Cs[w * 16 + quad * 4 + r][f * 16 + ml] = acc[f][r] * 0.125f;
    __syncthreads();

    const int rq = t >> 4;   // rows m0 + 4*rq + j
    const int cq = t & 15;   // cols n0 + 4*cq + q

    float4 av[4];
    #pragma unroll
    for (int j = 0; j < 4; ++j) av[j] = *(const float4*)&Cs[4 * rq + j][4 * cq];

    int mrow[4], mm[4];
    #pragma unroll
    for (int j = 0; j < 4; ++j) {
        mrow[j] = m0 + 4 * rq + j;
        mm[j]   = mask[b * N_ + mrow[j]];
    }
    const int ncol = n0 + 4 * cq;
    const int4 mnv = *(const int4*)(mask + b * N_ + ncol);
    const int mn[4] = { mnv.x, mnv.y, mnv.z, mnv.w };

    #pragma unroll
    for (int hh = 0; hh < H; ++hh) {
        const float4 be = *(const float4*)(biasfam + ((size_t)b * 2 * H + 2 * hh) * N_ + ncol);
        float bo[4];
        #pragma unroll
        for (int j = 0; j < 4; ++j)
            bo[j] = biasfam[((size_t)b * 2 * H + 2 * hh + 1) * N_ + mrow[j]];

        #pragma unroll
        for (int j = 0; j < 4; ++j) {
            const float* aj = (const float*)&av[j];
            float o[4] = { aj[0] + be.x + bo[j], aj[1] + be.y + bo[j],
                           aj[2] + be.z + bo[j], aj[3] + be.w + bo[j] };
            #pragma unroll
            for (int q = 0; q < 4; ++q) {
                if (!(mm[j] & mn[q])) o[q] -= NEGV;
                if (TRIL && (ncol + q) < mrow[j]) o[q] -= NEGV;
            }
            vf4_t ov;
            ov.x = o[0]; ov.y = o[1]; ov.z = o[2]; ov.w = o[3];
            __builtin_nontemporal_store(
                ov, (vf4_t*)(out + ((size_t)(b * H + hh) * N_ + mrow[j]) * N_ + ncol));
        }
    }
}

__global__ __launch_bounds__(256) void egp_all_kernel(
    const unsigned short* __restrict__ qbf, const unsigned short* __restrict__ kbf,
    const float* __restrict__ bias_e, const float* __restrict__ bias_h,
    const float* __restrict__ bias_t,
    const int* __restrict__ mask, float* __restrict__ out)
{
    __shared__ float Cs[64][68];

    const int t   = threadIdx.x;
    const int m0  = blockIdx.x * 64;
    const int n0  = blockIdx.y * 64;
    const int fam = blockIdx.z >> 3;
    const int b   = blockIdx.z & 7;

    const size_t ent_sz  = (size_t)B_ * 2 * N_ * N_;
    const size_t head_sz = (size_t)B_ * 12 * N_ * N_;
    const size_t fsl = (size_t)M_ * HS_;

    if (fam == 0) {
        egp_tile<2, true>(qbf, kbf, bias_e, mask, out, b, m0, n0, Cs, t);
    } else if (fam == 1) {
        egp_tile<12, false>(qbf + fsl, kbf + fsl, bias_h, mask,
                            out + ent_sz, b, m0, n0, Cs, t);
    } else {
        egp_tile<12, false>(qbf + 2 * fsl, kbf + 2 * fsl, bias_t, mask,
                            out + ent_sz + head_sz, b, m0, n0, Cs, t);
    }
}

// ---------------------------------------------------------------------------
extern "C" void kernel_launch(void* const* d_in, const int* in_sizes, int n_in,
                              void* d_out, int out_size, void* d_ws, size_t ws_size,
                              hipStream_t stream)
{
    const float* chars = (const float*)d_in[0];
    const int*   mask  = (const int*)d_in[1];
    const float* w1e = (const float*)d_in[2];
    const float* b1e = (const float*)d_in[3];
    const float* w2e = (const float*)d_in[4];
    const float* b2e = (const float*)d_in[5];
    const float* w1h = (const float*)d_in[6];
    const float* b1h = (const float*)d_in[7];
    const float* w2h = (const float*)d_in[8];
    const float* b2h = (const float*)d_in[9];
    const float* w1t = (const float*)d_in[10];
    const float* b1t = (const float*)d_in[11];
    const float* w2t = (const float*)d_in[12];
    const float* b2t = (const float*)d_in[13];

    float* out = (float*)d_out;

    // workspace layout
    unsigned short* qbf = (unsigned short*)d_ws;               // 3*4096*64 bf16
    unsigned short* kbf = qbf + (size_t)3 * M_ * HS_;          // 3*4096*64 bf16
    float* bias_e = (float*)(kbf + (size_t)3 * M_ * HS_);      // 8*4*512
    float* bias_h = bias_e + (size_t)B_ * 4 * N_;              // 8*24*512
    float* bias_t = bias_h + (size_t)B_ * 24 * N_;             // 8*24*512

    prep_kernel<<<dim3(128, 3), 256, 0, stream>>>(
        chars, w1e, b1e, w2e, b2e, w1h, b1h, w2h, b2h, w1t, b1t, w2t, b2t,
        qbf, kbf, bias_e, bias_h, bias_t);

    egp_all_kernel<<<dim3(8, 8, 24), 256, 0, stream>>>(
        qbf, kbf, bias_e, bias_h, bias_t, mask, out);
}

// Round 7
// 276.515 us; speedup vs baseline: 1.3337x; 1.0239x over previous
//
#include <hip/hip_runtime.h>
#include <cstddef>

namespace {
constexpr int B_ = 8;
constexpr int N_ = 512;
constexpr int D_ = 768;
constexpr int HS_ = 64;
constexpr int M_ = B_ * N_;   // 4096 rows (b*N + n)
constexpr int E_ = 2 * HS_;   // 128
constexpr float NEGV = 1000000000000.0f;
constexpr float LOG2_10000 = 13.287712379549449f;
}

typedef short mfrag_t __attribute__((ext_vector_type(8)));   // 8 bf16 (4 VGPRs)
typedef short mhalf_t __attribute__((ext_vector_type(4)));   // 4 bf16 (2 VGPRs)
typedef float macc_t  __attribute__((ext_vector_type(4)));   // 4 fp32
typedef float vf4_t   __attribute__((ext_vector_type(4)));   // clang vector for nt-store

__device__ __forceinline__ unsigned short bft(float x) {
    union { float f; unsigned u; } c; c.f = x;
    return (unsigned short)(c.u >> 16);   // truncate (RTZ)
}
__device__ __forceinline__ unsigned short bfrne(float x) {
    union { float f; unsigned u; } c; c.f = x;
    const unsigned r = c.u + 0x7FFFu + ((c.u >> 16) & 1u);
    return (unsigned short)(r >> 16);     // round-to-nearest-even
}

// ---------------------------------------------------------------------------
// Stage 1 (MFMA): h = chars @ w1^T + b1 (LDS only);
//   bias partial = (h_half @ w2_half^T [+ b2])*0.5  (fused, 2 halves summed in egp);
//   qbf/kbf = roped bf16 q/k in [row][k] fragment-ready layout (k-half per block).
// grid (128, 6): (m-tile, half + 2*fam), block 256 (4 waves).
// Tile M=32, Ncols=64 (half of E), KB=32. 768 blocks = 3/CU for latency hiding.
// ---------------------------------------------------------------------------
__global__ __launch_bounds__(256) void prep_kernel(
    const float* __restrict__ chars,
    const float* __restrict__ w1e, const float* __restrict__ b1e,
    const float* __restrict__ w2e, const float* __restrict__ b2e,
    const float* __restrict__ w1h, const float* __restrict__ b1h,
    const float* __restrict__ w2h, const float* __restrict__ b2h,
    const float* __restrict__ w1t, const float* __restrict__ b1t,
    const float* __restrict__ w2t, const float* __restrict__ b2t,
    unsigned short* __restrict__ qbf, unsigned short* __restrict__ kbf,
    float* __restrict__ bias_e, float* __restrict__ bias_h, float* __restrict__ bias_t)
{
    const int fam  = blockIdx.y >> 1;
    const int half = blockIdx.y & 1;
    const float* w1 = (fam == 0) ? w1e : (fam == 1) ? w1h : w1t;
    const float* b1 = (fam == 0) ? b1e : (fam == 1) ? b1h : b1t;
    const float* w2 = (fam == 0) ? w2e : (fam == 1) ? w2h : w2t;
    const float* b2 = (fam == 0) ? b2e : (fam == 1) ? b2h : b2t;
    const int H2 = (fam == 0) ? 4 : 24;
    // bias partial buffers: [half][b][h2][n] per family
    float* bout = ((fam == 0) ? bias_e : (fam == 1) ? bias_h : bias_t)
                  + (size_t)half * B_ * H2 * N_;
    unsigned short* qout = qbf + (size_t)fam * M_ * HS_;
    unsigned short* kout = kbf + (size_t)fam * M_ * HS_;
    const int m0 = blockIdx.x * 32;
    const int c0 = half * 64;          // global w1-col base of this block

    __shared__ unsigned short A_lds[32][40];   // [row][k], pad 32->40
    __shared__ unsigned short B_lds[64][40];   // [col(n) local][k]
    __shared__ float hs[32][68];               // h half-tile (local cols 0..63)

    const int t    = threadIdx.x;
    const int w    = t >> 6;          // wave 0..3
    const int lane = t & 63;
    const int ml   = lane & 15;
    const int quad = lane >> 4;
    const int wr16 = (w & 1) * 16;    // wave row strip
    const int wc32 = (w >> 1) * 32;   // wave col group (local)

    const int ar = t >> 3;            // A row 0..31
    const int ak = (t & 7) * 4;       // A k-offset (4 floats)
    const int bc = t >> 2;            // B local col 0..63
    const int bk = (t & 3) * 8;       // B k-offset (8 floats)

    const float* aptr = chars + (size_t)(m0 + ar) * D_ + ak;
    const float* bptr = w1 + (size_t)(c0 + bc) * D_ + bk;

    macc_t acc[2];
    acc[0] = (macc_t)0.0f; acc[1] = (macc_t)0.0f;

    float4 av0 = *(const float4*)(aptr);
    float4 bv0 = *(const float4*)(bptr);
    float4 bv1 = *(const float4*)(bptr + 4);

    for (int s = 0; s < 24; ++s) {
        {
            mhalf_t pa;
            pa[0] = (short)bft(av0.x); pa[1] = (short)bft(av0.y);
            pa[2] = (short)bft(av0.z); pa[3] = (short)bft(av0.w);
            *(mhalf_t*)&A_lds[ar][ak] = pa;
            mfrag_t pb;
            pb[0] = (short)bft(bv0.x); pb[1] = (short)bft(bv0.y);
            pb[2] = (short)bft(bv0.z); pb[3] = (short)bft(bv0.w);
            pb[4] = (short)bft(bv1.x); pb[5] = (short)bft(bv1.y);
            pb[6] = (short)bft(bv1.z); pb[7] = (short)bft(bv1.w);
            *(mfrag_t*)&B_lds[bc][bk] = pb;
        }
        __syncthreads();
        if (s < 23) {
            aptr += 32; bptr += 32;
            av0 = *(const float4*)(aptr);
            bv0 = *(const float4*)(bptr);
            bv1 = *(const float4*)(bptr + 4);
        }
        const mfrag_t afrag = *(const mfrag_t*)&A_lds[wr16 + ml][quad * 8];
        #pragma unroll
        for (int f = 0; f < 2; ++f) {
            const mfrag_t bfrag = *(const mfrag_t*)&B_lds[wc32 + f * 16 + ml][quad * 8];
            acc[f] = __builtin_amdgcn_mfma_f32_16x16x32_bf16(afrag, bfrag, acc[f], 0, 0, 0);
        }
        __syncthreads();
    }

    // C layout: local col = wc32 + f*16 + ml, row = wr16 + quad*4 + r
    #pragma unroll
    for (int f = 0; f < 2; ++f) {
        const int col = wc32 + f * 16 + ml;
        const float bb1 = b1[c0 + col];
        #pragma unroll
        for (int r = 0; r < 4; ++r)
            hs[wr16 + quad * 4 + r][col] = acc[f][r] + bb1;
    }
    __syncthreads();

    // q/k extraction (+rope for fam 0) -> bf16 [row][k], k-range [half*32, +32).
    // local h col 4i..4i+3 (i = local pair idx 0..15) -> q[2i],k[2i],q[2i+1],k[2i+1]
    {
        const int row = t >> 3;          // 0..31
        const int kg  = t & 7;           // 2 pairs per thread
        const float pos = (float)((m0 & 511) + row);
        unsigned short qv[4], kv[4];
        #pragma unroll
        for (int p = 0; p < 2; ++p) {
            const int il = kg * 2 + p;   // local pair 0..15
            const float q0 = hs[row][4 * il + 0];
            const float k0 = hs[row][4 * il + 1];
            const float q1 = hs[row][4 * il + 2];
            const float k1 = hs[row][4 * il + 3];
            if (fam == 0) {
                const int ig = half * 16 + il;
                const float inv = exp2f(-(float)ig * (LOG2_10000 / 32.0f));
                float sn, cs;
                sincosf(pos * inv, &sn, &cs);
                qv[2 * p + 0] = bfrne(q0 * cs - q1 * sn);
                qv[2 * p + 1] = bfrne(q1 * cs + q0 * sn);
                kv[2 * p + 0] = bfrne(k0 * cs - k1 * sn);
                kv[2 * p + 1] = bfrne(k1 * cs + k0 * sn);
            } else {
                qv[2 * p + 0] = bfrne(q0);
                qv[2 * p + 1] = bfrne(q1);
                kv[2 * p + 0] = bfrne(k0);
                kv[2 * p + 1] = bfrne(k1);
            }
        }
        const size_t off = (size_t)(m0 + row) * HS_ + half * 32 + kg * 4;
        *(mhalf_t*)(qout + off) = *(const mhalf_t*)&qv[0];
        *(mhalf_t*)(kout + off) = *(const mhalf_t*)&kv[0];
    }

    // fused partial bias: row = t&31, heads h2 = (t>>5) + 8p; dot over 64 local e.
    {
        const int row = t & 31;
        const int h2b = t >> 5;          // 0..7
        const int bb  = m0 >> 9;
        const int nb  = (m0 & 511) + row;
        float accv[3] = {0, 0, 0};
        for (int e0 = 0; e0 < 64; e0 += 16) {
            float4 hv0 = *(const float4*)&hs[row][e0];
            float4 hv1 = *(const float4*)&hs[row][e0 + 4];
            float4 hv2 = *(const float4*)&hs[row][e0 + 8];
            float4 hv3 = *(const float4*)&hs[row][e0 + 12];
            int p = 0;
            for (int h2 = h2b; h2 < H2; h2 += 8, ++p) {
                const float* wr = w2 + (size_t)h2 * E_ + c0 + e0;
                const float4 w0 = *(const float4*)(wr);
                const float4 w1v = *(const float4*)(wr + 4);
                const float4 w2v = *(const float4*)(wr + 8);
                const float4 w3v = *(const float4*)(wr + 12);
                accv[p] += hv0.x * w0.x + hv0.y * w0.y + hv0.z * w0.z + hv0.w * w0.w
                         + hv1.x * w1v.x + hv1.y * w1v.y + hv1.z * w1v.z + hv1.w * w1v.w
                         + hv2.x * w2v.x + hv2.y * w2v.y + hv2.z * w2v.z + hv2.w * w2v.w
                         + hv3.x * w3v.x + hv3.y * w3v.y + hv3.z * w3v.z + hv3.w * w3v.w;
            }
        }
        int p = 0;
        for (int h2 = h2b; h2 < H2; h2 += 8, ++p) {
            const float bterm = (half == 0) ? b2[h2] : 0.0f;
            bout[((size_t)bb * H2 + h2) * N_ + nb] = (accv[p] + bterm) * 0.5f;
        }
    }
}

// ---------------------------------------------------------------------------
// Stage 2: MFMA QK^T (fragments direct from global bf16 q/k) + bias + masks.
// grid (8, 8, 24): (m-tile, n-tile, fam*8+b), block 256. 64x64 tile, K=64.
// bias = sum of the two half-partials. Output stores non-temporal.
// ---------------------------------------------------------------------------
template <int H, bool TRIL>
__device__ __forceinline__ void egp_tile(
    const unsigned short* __restrict__ qf, const unsigned short* __restrict__ kf,
    const float* __restrict__ bias0, const float* __restrict__ bias1,
    const int* __restrict__ mask,
    float* __restrict__ out, int b, int m0, int n0, float (*Cs)[68], int t)
{
    const int w    = t >> 6;
    const int lane = t & 63;
    const int ml   = lane & 15;
    const int quad = lane >> 4;

    macc_t acc[4];
    #pragma unroll
    for (int f = 0; f < 4; ++f) acc[f] = (macc_t)0.0f;

    const unsigned short* qrow = qf + (size_t)(b * N_ + m0 + w * 16 + ml) * HS_ + quad * 8;
    const unsigned short* krow = kf + (size_t)(b * N_ + n0 + ml) * HS_ + quad * 8;

    #pragma unroll
    for (int s = 0; s < 2; ++s) {
        const mfrag_t af = *(const mfrag_t*)(qrow + s * 32);
        #pragma unroll
        for (int f = 0; f < 4; ++f) {
            const mfrag_t bf = *(const mfrag_t*)(krow + (size_t)f * 16 * HS_ + s * 32);
            acc[f] = __builtin_amdgcn_mfma_f32_16x16x32_bf16(af, bf, acc[f], 0, 0, 0);
        }
    }

    // C layout -> LDS: row = w*16 + quad*4 + r, col = f*16 + ml  (scaled)
    #pragma unroll
    for (int f = 0; f < 4; ++f)
        #pragma unroll
        for (int r = 0; r < 4; ++r)
            Cs[w * 16 + quad * 4 + r][f * 16 + ml] = acc[f][r] * 0.125f;
    __syncthreads();

    const int rq = t >> 4;   // rows m0 + 4*rq + j
    const int cq = t & 15;   // cols n0 + 4*cq + q

    float4 av[4];
    #pragma unroll
    for (int j = 0; j < 4; ++j) av[j] = *(const float4*)&Cs[4 * rq + j][4 * cq];

    int mrow[4], mm[4];
    #pragma unroll
    for (int j = 0; j < 4; ++j) {
        mrow[j] = m0 + 4 * rq + j;
        mm[j]   = mask[b * N_ + mrow[j]];
    }
    const int ncol = n0 + 4 * cq;
    const int4 mnv = *(const int4*)(mask + b * N_ + ncol);
    const int mn[4] = { mnv.x, mnv.y, mnv.z, mnv.w };

    #pragma unroll
    for (int hh = 0; hh < H; ++hh) {
        const size_t be_idx = ((size_t)b * 2 * H + 2 * hh) * N_ + ncol;
        const float4 be0 = *(const float4*)(bias0 + be_idx);
        const float4 be1 = *(const float4*)(bias1 + be_idx);
        const float4 be = make_float4(be0.x + be1.x, be0.y + be1.y,
                                      be0.z + be1.z, be0.w + be1.w);
        float bo[4];
        #pragma unroll
        for (int j = 0; j < 4; ++j) {
            const size_t bo_idx = ((size_t)b * 2 * H + 2 * hh + 1) * N_ + mrow[j];
            bo[j] = bias0[bo_idx] + bias1[bo_idx];
        }

        #pragma unroll
        for (int j = 0; j < 4; ++j) {
            const float* aj = (const float*)&av[j];
            float o[4] = { aj[0] + be.x + bo[j], aj[1] + be.y + bo[j],
                           aj[2] + be.z + bo[j], aj[3] + be.w + bo[j] };
            #pragma unroll
            for (int q = 0; q < 4; ++q) {
                if (!(mm[j] & mn[q])) o[q] -= NEGV;
                if (TRIL && (ncol + q) < mrow[j]) o[q] -= NEGV;
            }
            vf4_t ov;
            ov.x = o[0]; ov.y = o[1]; ov.z = o[2]; ov.w = o[3];
            __builtin_nontemporal_store(
                ov, (vf4_t*)(out + ((size_t)(b * H + hh) * N_ + mrow[j]) * N_ + ncol));
        }
    }
}

__global__ __launch_bounds__(256) void egp_all_kernel(
    const unsigned short* __restrict__ qbf, const unsigned short* __restrict__ kbf,
    const float* __restrict__ bias_e, const float* __restrict__ bias_h,
    const float* __restrict__ bias_t,
    const int* __restrict__ mask, float* __restrict__ out)
{
    __shared__ float Cs[64][68];

    const int t   = threadIdx.x;
    const int m0  = blockIdx.x * 64;
    const int n0  = blockIdx.y * 64;
    const int fam = blockIdx.z >> 3;
    const int b   = blockIdx.z & 7;

    const size_t ent_sz  = (size_t)B_ * 2 * N_ * N_;
    const size_t head_sz = (size_t)B_ * 12 * N_ * N_;
    const size_t fsl = (size_t)M_ * HS_;
    const size_t ehalf = (size_t)B_ * 4 * N_;    // ent partial-buffer stride
    const size_t hhalf = (size_t)B_ * 24 * N_;   // head/tail partial-buffer stride

    if (fam == 0) {
        egp_tile<2, true>(qbf, kbf, bias_e, bias_e + ehalf, mask, out, b, m0, n0, Cs, t);
    } else if (fam == 1) {
        egp_tile<12, false>(qbf + fsl, kbf + fsl, bias_h, bias_h + hhalf, mask,
                            out + ent_sz, b, m0, n0, Cs, t);
    } else {
        egp_tile<12, false>(qbf + 2 * fsl, kbf + 2 * fsl, bias_t, bias_t + hhalf, mask,
                            out + ent_sz + head_sz, b, m0, n0, Cs, t);
    }
}

// ---------------------------------------------------------------------------
extern "C" void kernel_launch(void* const* d_in, const int* in_sizes, int n_in,
                              void* d_out, int out_size, void* d_ws, size_t ws_size,
                              hipStream_t stream)
{
    const float* chars = (const float*)d_in[0];
    const int*   mask  = (const int*)d_in[1];
    const float* w1e = (const float*)d_in[2];
    const float* b1e = (const float*)d_in[3];
    const float* w2e = (const float*)d_in[4];
    const float* b2e = (const float*)d_in[5];
    const float* w1h = (const float*)d_in[6];
    const float* b1h = (const float*)d_in[7];
    const float* w2h = (const float*)d_in[8];
    const float* b2h = (const float*)d_in[9];
    const float* w1t = (const float*)d_in[10];
    const float* b1t = (const float*)d_in[11];
    const float* w2t = (const float*)d_in[12];
    const float* b2t = (const float*)d_in[13];

    float* out = (float*)d_out;

    // workspace layout
    unsigned short* qbf = (unsigned short*)d_ws;               // 3*4096*64 bf16
    unsigned short* kbf = qbf + (size_t)3 * M_ * HS_;          // 3*4096*64 bf16
    float* bias_e = (float*)(kbf + (size_t)3 * M_ * HS_);      // 2 halves * 8*4*512
    float* bias_h = bias_e + (size_t)2 * B_ * 4 * N_;          // 2 halves * 8*24*512
    float* bias_t = bias_h + (size_t)2 * B_ * 24 * N_;         // 2 halves * 8*24*512

    prep_kernel<<<dim3(128, 6), 256, 0, stream>>>(
        chars, w1e, b1e, w2e, b2e, w1h, b1h, w2h, b2h, w1t, b1t, w2t, b2t,
        qbf, kbf, bias_e, bias_h, bias_t);

    egp_all_kernel<<<dim3(8, 8, 24), 256, 0, stream>>>(
        qbf, kbf, bias_e, bias_h, bias_t, mask, out);
}